// Round 1
// baseline (2073.889 us; speedup 1.0000x reference)
//
#include <hip/hip_runtime.h>
#include <cstdint>

#define B_   32
#define T1_  2048
#define T2_  512
#define CATT 100

// ---------------------------------------------------------------------------
// Generic 1D-conv as tiled GEMM: Y[b,co,t] = bias[co] + sum_{ci,dk} X[b,ci,t+dk-pad]*W[co,ci,dk]
// K-dim index kd = ci*Kw + dk, so W[co][kd] is contiguous (W layout [Cout,Cin,Kw]).
// 64x64 output tile, 4x4 per thread, fp32.
// ---------------------------------------------------------------------------
__global__ __launch_bounds__(256) void conv_gemm(
    const float* __restrict__ X, const float* __restrict__ W,
    const float* __restrict__ bias, float* __restrict__ Y,
    int Cin, int Cout, int T, int Kw, int pad, int do_relu)
{
    __shared__ float Ws[8][64];
    __shared__ float Xs[8][64];
    const int b   = blockIdx.z;
    const int co0 = blockIdx.y * 64;
    const int t0  = blockIdx.x * 64;
    const int CK  = Cin * Kw;
    const int tid = threadIdx.x;
    const int tx  = tid & 15, ty = tid >> 4;
    const float* Xb = X + (size_t)b * Cin * T;
    float acc[4][4] = {};

    for (int kk = 0; kk < CK; kk += 8) {
        {   // W tile: row = kd offset (8), col = co offset (64); coalesced along kd
            int col = tid >> 2;
            int r0  = (tid & 3) * 2;
            int co  = co0 + col;
#pragma unroll
            for (int u = 0; u < 2; ++u) {
                int kd = kk + r0 + u;
                float v = 0.f;
                if (co < Cout && kd < CK) v = W[(size_t)co * CK + kd];
                Ws[r0 + u][col] = v;
            }
        }
        {   // X tile: row = kd offset, col = t offset; coalesced along t
            int col = tid & 63;
            int r0  = (tid >> 6) * 2;
#pragma unroll
            for (int u = 0; u < 2; ++u) {
                int kd = kk + r0 + u;
                float v = 0.f;
                if (kd < CK) {
                    int ci = kd / Kw;
                    int dk = kd - ci * Kw;
                    int t  = t0 + col + dk - pad;
                    if (t >= 0 && t < T) v = Xb[(size_t)ci * T + t];
                }
                Xs[r0 + u][col] = v;
            }
        }
        __syncthreads();
#pragma unroll
        for (int kr = 0; kr < 8; ++kr) {
            float4 av = *(const float4*)&Ws[kr][ty * 4];
            float4 xv = *(const float4*)&Xs[kr][tx * 4];
            float a[4] = {av.x, av.y, av.z, av.w};
            float x[4] = {xv.x, xv.y, xv.z, xv.w};
#pragma unroll
            for (int i = 0; i < 4; ++i)
#pragma unroll
                for (int j = 0; j < 4; ++j)
                    acc[i][j] += a[i] * x[j];
        }
        __syncthreads();
    }
#pragma unroll
    for (int i = 0; i < 4; ++i) {
        int co = co0 + ty * 4 + i;
        if (co < Cout) {
            float bv = bias[co];
            float4 o;
            o.x = acc[i][0] + bv; o.y = acc[i][1] + bv;
            o.z = acc[i][2] + bv; o.w = acc[i][3] + bv;
            if (do_relu) {
                o.x = fmaxf(o.x, 0.f); o.y = fmaxf(o.y, 0.f);
                o.z = fmaxf(o.z, 0.f); o.w = fmaxf(o.w, 0.f);
            }
            *(float4*)&Y[((size_t)b * Cout + co) * T + t0 + tx * 4] = o;
        }
    }
}

// ---------------------------------------------------------------------------
// Fused attention: qk (K=100) + |q|^2 + |k|^2 -> raw -> log_softmax + log(prior)
// -> out_logp ; masked softmax -> out_attn.
// Block = 256 threads handles (b, 32 rows of T1). k staged in LDS in 4 chunks
// of 128. Each thread: rows r = g+8i (g=tid>>5, i<4), t2 = chunk*128 + xl*4+j.
// Row reductions = shuffle within 32-lane half-wave (all lanes share g).
// ---------------------------------------------------------------------------
__global__ __launch_bounds__(256) void attn_kernel(
    const float* __restrict__ q,     // [B,100,T1]
    const float* __restrict__ k,     // [B,100,T2]
    const unsigned char* __restrict__ mask, // [B,T2] (bool bytes), nonzero = masked
    const float* __restrict__ prior, // [B,T1,T2]
    float* __restrict__ out_attn,    // [B,T1,T2]
    float* __restrict__ out_logp)    // [B,T1,T2]
{
    __shared__ float qt[CATT][32];
    __shared__ float ks[CATT][128];
    __shared__ float k2s[T2_];
    __shared__ float q2s[32];
    __shared__ unsigned char msk[T2_];

    const int b   = blockIdx.y;
    const int t0  = blockIdx.x * 32;
    const int tid = threadIdx.x;
    const int g   = tid >> 5;
    const int xl  = tid & 31;

    const float* qb = q + (size_t)b * CATT * T1_ + t0;
    for (int li = tid; li < CATT * 32; li += 256) {
        int c = li >> 5, r = li & 31;
        qt[c][r] = qb[(size_t)c * T1_ + r];
    }
    for (int li = tid; li < T2_; li += 256) msk[li] = mask[(size_t)b * T2_ + li];
    __syncthreads();
    if (tid < 32) {
        float s = 0.f;
        for (int c = 0; c < CATT; ++c) { float v = qt[c][tid]; s += v * v; }
        q2s[tid] = s;
    }

    float acc[4][16];
#pragma unroll
    for (int i = 0; i < 4; ++i)
#pragma unroll
        for (int m = 0; m < 16; ++m) acc[i][m] = 0.f;

    const float* kb = k + (size_t)b * CATT * T2_;
    for (int chunk = 0; chunk < 4; ++chunk) {
        __syncthreads();   // protect ks reuse across chunks
        for (int li = tid; li < CATT * 128; li += 256) {
            int c = li >> 7, x = li & 127;
            ks[c][x] = kb[(size_t)c * T2_ + chunk * 128 + x];
        }
        __syncthreads();
        if (tid < 128) {
            float s = 0.f;
            for (int c = 0; c < CATT; ++c) { float v = ks[c][tid]; s += v * v; }
            k2s[chunk * 128 + tid] = s;
        }
#pragma unroll 2
        for (int c = 0; c < CATT; ++c) {
            float4 kv = *(const float4*)&ks[c][xl * 4];
#pragma unroll
            for (int i = 0; i < 4; ++i) {
                float qv = qt[c][g + 8 * i];
                acc[i][chunk * 4 + 0] += qv * kv.x;
                acc[i][chunk * 4 + 1] += qv * kv.y;
                acc[i][chunk * 4 + 2] += qv * kv.z;
                acc[i][chunk * 4 + 3] += qv * kv.w;
            }
        }
    }
    __syncthreads();   // k2s / q2s visible

    const float NEG_INF = -__builtin_huge_valf();
    const size_t outoff = ((size_t)b * T1_ + t0) * T2_;

#pragma unroll 1
    for (int i = 0; i < 4; ++i) {
        const int r = g + 8 * i;
        const float q2v = q2s[r];
        // raw = 1e-3*qk - 5e-4*(|q|^2 + |k|^2)
        float M1 = NEG_INF;
#pragma unroll
        for (int m = 0; m < 16; ++m) {
            int t2 = (m >> 2) * 128 + xl * 4 + (m & 3);
            float raw = 1e-3f * acc[i][m] - 5e-4f * (q2v + k2s[t2]);
            acc[i][m] = raw;
            M1 = fmaxf(M1, raw);
        }
#pragma unroll
        for (int d = 1; d <= 16; d <<= 1) M1 = fmaxf(M1, __shfl_xor(M1, d, 64));
        float S1 = 0.f;
#pragma unroll
        for (int m = 0; m < 16; ++m) S1 += __expf(acc[i][m] - M1);
#pragma unroll
        for (int d = 1; d <= 16; d <<= 1) S1 += __shfl_xor(S1, d, 64);
        const float L1 = M1 + __logf(S1);

        const size_t rowbase = outoff + (size_t)r * T2_;
        const float* pr = prior + rowbase;
        float* o1 = out_logp + rowbase;
#pragma unroll
        for (int ch = 0; ch < 4; ++ch) {
            int t2b = ch * 128 + xl * 4;
            float4 pv = *(const float4*)&pr[t2b];
            float4 o;
            o.x = acc[i][ch * 4 + 0] - L1 + __logf(pv.x + 1e-8f);
            o.y = acc[i][ch * 4 + 1] - L1 + __logf(pv.y + 1e-8f);
            o.z = acc[i][ch * 4 + 2] - L1 + __logf(pv.z + 1e-8f);
            o.w = acc[i][ch * 4 + 3] - L1 + __logf(pv.w + 1e-8f);
            *(float4*)&o1[t2b] = o;
            acc[i][ch * 4 + 0] = o.x; acc[i][ch * 4 + 1] = o.y;
            acc[i][ch * 4 + 2] = o.z; acc[i][ch * 4 + 3] = o.w;
        }
        // masked softmax
        float M2 = NEG_INF;
#pragma unroll
        for (int m = 0; m < 16; ++m) {
            int t2 = (m >> 2) * 128 + xl * 4 + (m & 3);
            float am = msk[t2] ? NEG_INF : acc[i][m];
            acc[i][m] = am;
            M2 = fmaxf(M2, am);
        }
#pragma unroll
        for (int d = 1; d <= 16; d <<= 1) M2 = fmaxf(M2, __shfl_xor(M2, d, 64));
        float S2 = 0.f;
#pragma unroll
        for (int m = 0; m < 16; ++m) S2 += __expf(acc[i][m] - M2);
#pragma unroll
        for (int d = 1; d <= 16; d <<= 1) S2 += __shfl_xor(S2, d, 64);
        const float inv = 1.0f / S2;

        float* o0 = out_attn + rowbase;
#pragma unroll
        for (int ch = 0; ch < 4; ++ch) {
            int t2b = ch * 128 + xl * 4;
            float4 o;
            o.x = __expf(acc[i][ch * 4 + 0] - M2) * inv;
            o.y = __expf(acc[i][ch * 4 + 1] - M2) * inv;
            o.z = __expf(acc[i][ch * 4 + 2] - M2) * inv;
            o.w = __expf(acc[i][ch * 4 + 3] - M2) * inv;
            *(float4*)&o0[t2b] = o;
        }
    }
}

extern "C" void kernel_launch(void* const* d_in, const int* in_sizes, int n_in,
                              void* d_out, int out_size, void* d_ws, size_t ws_size,
                              hipStream_t stream)
{
    const float* queries = (const float*)d_in[0];   // [32,100,2048]
    const float* keys    = (const float*)d_in[1];   // [32,512,512]
    // d_in[2] = query_lens (unused by reference)
    const unsigned char* mask = (const unsigned char*)d_in[3]; // [32,512,1] bool
    const float* prior   = (const float*)d_in[4];   // [32,2048,512]
    const float* kW1 = (const float*)d_in[5];
    const float* kb1 = (const float*)d_in[6];
    const float* kW2 = (const float*)d_in[7];
    const float* kb2 = (const float*)d_in[8];
    const float* qW1 = (const float*)d_in[9];
    const float* qb1 = (const float*)d_in[10];
    const float* qW2 = (const float*)d_in[11];
    const float* qb2 = (const float*)d_in[12];
    const float* qW3 = (const float*)d_in[13];
    const float* qb3 = (const float*)d_in[14];

    // workspace layout (floats):
    //   region0 [0, 16777216): k1 [32,1024,512] -> then q1 [32,200,2048] -> then q [32,100,2048]
    //   region1 [16777216, +1638400): k [32,100,512]
    //   region2 [18415616, +6553600): q2 [32,100,2048]
    // total = 24,969,216 floats = ~95.3 MiB
    float* ws  = (float*)d_ws;
    float* k1  = ws;
    float* kkp = ws + 16777216;
    float* q1  = ws;
    float* q2b = ws + 16777216 + 1638400;
    float* qqp = ws;   // q final overwrites q1 region (q1 dead after conv D)

    float* out_attn = (float*)d_out;
    float* out_logp = (float*)d_out + (size_t)B_ * T1_ * T2_;

    dim3 blk(256);
    // key proj: conv(512->1024,k3,pad1)+relu ; conv(1024->100,k1)
    conv_gemm<<<dim3(T2_ / 64, 1024 / 64, B_), blk, 0, stream>>>(keys, kW1, kb1, k1, 512, 1024, T2_, 3, 1, 1);
    conv_gemm<<<dim3(T2_ / 64, 2, B_), blk, 0, stream>>>(k1, kW2, kb2, kkp, 1024, 100, T2_, 1, 0, 0);
    // query proj: conv(100->200,k3,pad1)+relu ; conv(200->100,k1)+relu ; conv(100->100,k1)
    conv_gemm<<<dim3(T1_ / 64, 4, B_), blk, 0, stream>>>(queries, qW1, qb1, q1, 100, 200, T1_, 3, 1, 1);
    conv_gemm<<<dim3(T1_ / 64, 2, B_), blk, 0, stream>>>(q1, qW2, qb2, q2b, 200, 100, T1_, 1, 0, 1);
    conv_gemm<<<dim3(T1_ / 64, 2, B_), blk, 0, stream>>>(q2b, qW3, qb3, qqp, 100, 100, T1_, 1, 0, 0);
    // fused distance-attention + double softmax
    attn_kernel<<<dim3(T1_ / 32, B_), blk, 0, stream>>>(qqp, kkp, mask, prior, out_attn, out_logp);

    (void)in_sizes; (void)n_in; (void)out_size; (void)ws_size;
}

// Round 2
// 983.230 us; speedup vs baseline: 2.1093x; 2.1093x over previous
//
#include <hip/hip_runtime.h>
#include <cstdint>

#define B_   32
#define T1_  2048
#define T2_  512
#define CATT 100

typedef __attribute__((ext_vector_type(8))) short short8;   // 8 x bf16 (4 VGPRs)
typedef __attribute__((ext_vector_type(4))) float f32x4;

__device__ __forceinline__ unsigned short f2bf(float f) {
    union { float f; unsigned u; } x; x.f = f;
    unsigned r = x.u + 0x7fffu + ((x.u >> 16) & 1u);   // RNE
    return (unsigned short)(r >> 16);
}
__device__ __forceinline__ float bf2f(unsigned short u) {
    union { unsigned u; float f; } x; x.u = ((unsigned)u) << 16;
    return x.f;
}

__device__ __forceinline__ void async16(const unsigned short* g, unsigned short* l) {
    __builtin_amdgcn_global_load_lds(
        (const __attribute__((address_space(1))) unsigned int*)g,
        (__attribute__((address_space(3))) unsigned int*)l, 16, 0, 0);
}

// ---------------------------------------------------------------------------
// Weight cast+pad: W fp32 [Cout][CK] -> Wb bf16 [Mpad][CKp], zero padding.
// ---------------------------------------------------------------------------
__global__ void cast_w(const float* __restrict__ W, unsigned short* __restrict__ Wb,
                       int Cout, int CK, int CKp, int Mpad)
{
    int idx = blockIdx.x * 256 + threadIdx.x;
    if (idx >= Mpad * CKp) return;
    int m = idx / CKp, c = idx - m * CKp;
    float v = (m < Cout && c < CK) ? W[(size_t)m * CK + c] : 0.f;
    Wb[idx] = f2bf(v);
}

// ---------------------------------------------------------------------------
// im2col for k=3, pad=1: X fp32 [B][Cin][T] -> Bmat bf16 [B][T][CKp],
// Bmat[b][t][ci*3+dk] = X[b][ci][t+dk-1] (0 outside), cols >= Cin*3 zero.
// ---------------------------------------------------------------------------
__global__ void im2col_k3(const float* __restrict__ X, unsigned short* __restrict__ Bmat,
                          int Cin, int T, int CKp)
{
    int b = blockIdx.y;
    int idx = blockIdx.x * 256 + threadIdx.x;
    if (idx >= T * CKp) return;
    int t = idx / CKp, c = idx - t * CKp;
    int CK = Cin * 3;
    float v = 0.f;
    if (c < CK) {
        int ci = c / 3, dk = c - ci * 3;
        int ts = t + dk - 1;
        if (ts >= 0 && ts < T) v = X[((size_t)b * Cin + ci) * T + ts];
    }
    Bmat[(size_t)b * T * CKp + idx] = f2bf(v);
}

// ---------------------------------------------------------------------------
// bf16 MFMA GEMM (m97 structure): D[co][t] = sum_ck Wb[co][ck] * Bmat[t][ck].
// 128x128 tile, BK=32, 256 thr = 4 waves in 2x2, each wave 64x64 (4x4 frags
// of 16x16x32). global_load_lds 16B staging; single-buffer 2-barrier K-loop.
// TRANS=1: epilogue stages tile in LDS, stores Y as [b][t][Mpad] bf16
//          (im2col layout for the next k=1 conv) with 16B coalesced stores.
// TRANS=0: stores Y as [b][Mpad][t] bf16 (consumed by attention).
// ---------------------------------------------------------------------------
template<int TRANS, int RELU>
__global__ __launch_bounds__(256) void gemm_conv(
    const unsigned short* __restrict__ A,   // [Mpad][CK] bf16 weights (padded)
    const unsigned short* __restrict__ Bm,  // [B][N][CK] bf16 im2col
    const float* __restrict__ bias,         // [Cout] fp32
    unsigned short* __restrict__ Y,
    int Cout, int CK, int N, int Mpad)
{
    __shared__ __align__(16) unsigned char smem[35328];
    unsigned short* Al = (unsigned short*)smem;          // [128][32]
    unsigned short* Bl = Al + 4096;                      // [128][32]
    unsigned short* Ct = (unsigned short*)smem;          // [128][136] epilogue
    float* biasS = (float*)(smem + 34816);               // [128]

    const int b   = blockIdx.z;
    const int co0 = blockIdx.y * 128;
    const int t0  = blockIdx.x * 128;
    const int tid = threadIdx.x;
    const int wave = tid >> 6, lane = tid & 63;
    const int lm = lane & 15, kg = lane >> 4;
    const int mbase = (wave >> 1) * 64, nbase = (wave & 1) * 64;

    if (tid < 128) biasS[tid] = (co0 + tid < Cout) ? bias[co0 + tid] : 0.f;

    const unsigned short* Ab = A + (size_t)co0 * CK;
    const unsigned short* Bb = Bm + ((size_t)b * N + t0) * CK;
    const int rL = lane >> 2;          // row-within-16 for staging
    const int cA = (lane & 3) * 8;     // col element offset for staging

    f32x4 acc[4][4];
#pragma unroll
    for (int mi = 0; mi < 4; ++mi)
#pragma unroll
        for (int ni = 0; ni < 4; ++ni) acc[mi][ni] = (f32x4){0.f, 0.f, 0.f, 0.f};

    for (int kk = 0; kk < CK; kk += 32) {
        __syncthreads();
#pragma unroll
        for (int i = 0; i < 2; ++i) {
            int R0 = i * 64 + wave * 16;   // wave-uniform
            async16(Ab + (size_t)(R0 + rL) * CK + kk + cA, Al + R0 * 32);
            async16(Bb + (size_t)(R0 + rL) * CK + kk + cA, Bl + R0 * 32);
        }
        __syncthreads();
        short8 av[4], bv[4];
#pragma unroll
        for (int mi = 0; mi < 4; ++mi)
            av[mi] = *(const short8*)(Al + (mbase + mi * 16 + lm) * 32 + kg * 8);
#pragma unroll
        for (int ni = 0; ni < 4; ++ni)
            bv[ni] = *(const short8*)(Bl + (nbase + ni * 16 + lm) * 32 + kg * 8);
#pragma unroll
        for (int mi = 0; mi < 4; ++mi)
#pragma unroll
            for (int ni = 0; ni < 4; ++ni)
                acc[mi][ni] = __builtin_amdgcn_mfma_f32_16x16x32_bf16(
                    av[mi], bv[ni], acc[mi][ni], 0, 0, 0);
    }
    __syncthreads();

    if (TRANS) {
        // stage bf16 tile transposed: Ct[t_local][co_local], stride 136
#pragma unroll
        for (int mi = 0; mi < 4; ++mi)
#pragma unroll
            for (int ni = 0; ni < 4; ++ni)
#pragma unroll
                for (int r = 0; r < 4; ++r) {
                    int co_l = mbase + mi * 16 + kg * 4 + r;
                    int t_l  = nbase + ni * 16 + lm;
                    float v = acc[mi][ni][r] + biasS[co_l];
                    if (RELU) v = fmaxf(v, 0.f);
                    Ct[t_l * 136 + co_l] = f2bf(v);
                }
        __syncthreads();
        unsigned short* Yb = Y + ((size_t)b * N + t0) * Mpad + co0;
        int c0 = (tid & 15) * 8;
#pragma unroll
        for (int p = 0; p < 8; ++p) {
            int r = (tid >> 4) + p * 16;
            *(uint4*)(Yb + (size_t)r * Mpad + c0) = *(const uint4*)(Ct + r * 136 + c0);
        }
    } else {
#pragma unroll
        for (int mi = 0; mi < 4; ++mi)
#pragma unroll
            for (int ni = 0; ni < 4; ++ni)
#pragma unroll
                for (int r = 0; r < 4; ++r) {
                    int co_l = mbase + mi * 16 + kg * 4 + r;
                    int t_l  = nbase + ni * 16 + lm;
                    float v = acc[mi][ni][r] + biasS[co_l];
                    if (RELU) v = fmaxf(v, 0.f);
                    Y[((size_t)b * Mpad + co0 + co_l) * N + t0 + t_l] = f2bf(v);
                }
    }
}

// ---------------------------------------------------------------------------
// Fused attention (fp32 math, bf16 inputs [B][128][T] with valid rows < 100):
// qk + |q|^2 + |k|^2 -> raw -> log_softmax + log(prior) -> out_logp ;
// masked softmax -> out_attn. Same structure as round 1.
// ---------------------------------------------------------------------------
__global__ __launch_bounds__(256) void attn_kernel(
    const unsigned short* __restrict__ q,   // [B,128,T1] bf16
    const unsigned short* __restrict__ k,   // [B,128,T2] bf16
    const unsigned char* __restrict__ mask, // [B,T2]
    const float* __restrict__ prior,        // [B,T1,T2]
    float* __restrict__ out_attn,
    float* __restrict__ out_logp)
{
    __shared__ float qt[CATT][32];
    __shared__ float ks[CATT][128];
    __shared__ float k2s[T2_];
    __shared__ float q2s[32];
    __shared__ unsigned char msk[T2_];

    const int b   = blockIdx.y;
    const int t0  = blockIdx.x * 32;
    const int tid = threadIdx.x;
    const int g   = tid >> 5;
    const int xl  = tid & 31;

    const unsigned short* qb = q + (size_t)b * 128 * T1_ + t0;
    for (int li = tid; li < CATT * 32; li += 256) {
        int c = li >> 5, r = li & 31;
        qt[c][r] = bf2f(qb[(size_t)c * T1_ + r]);
    }
    for (int li = tid; li < T2_; li += 256) msk[li] = mask[(size_t)b * T2_ + li];
    __syncthreads();
    if (tid < 32) {
        float s = 0.f;
        for (int c = 0; c < CATT; ++c) { float v = qt[c][tid]; s += v * v; }
        q2s[tid] = s;
    }

    float acc[4][16];
#pragma unroll
    for (int i = 0; i < 4; ++i)
#pragma unroll
        for (int m = 0; m < 16; ++m) acc[i][m] = 0.f;

    const unsigned short* kb = k + (size_t)b * 128 * T2_;
    for (int chunk = 0; chunk < 4; ++chunk) {
        __syncthreads();
        for (int li = tid; li < CATT * 128; li += 256) {
            int c = li >> 7, x = li & 127;
            ks[c][x] = bf2f(kb[(size_t)c * T2_ + chunk * 128 + x]);
        }
        __syncthreads();
        if (tid < 128) {
            float s = 0.f;
            for (int c = 0; c < CATT; ++c) { float v = ks[c][tid]; s += v * v; }
            k2s[chunk * 128 + tid] = s;
        }
#pragma unroll 2
        for (int c = 0; c < CATT; ++c) {
            float4 kv = *(const float4*)&ks[c][xl * 4];
#pragma unroll
            for (int i = 0; i < 4; ++i) {
                float qv = qt[c][g + 8 * i];
                acc[i][chunk * 4 + 0] += qv * kv.x;
                acc[i][chunk * 4 + 1] += qv * kv.y;
                acc[i][chunk * 4 + 2] += qv * kv.z;
                acc[i][chunk * 4 + 3] += qv * kv.w;
            }
        }
    }
    __syncthreads();

    const float NEG_INF = -__builtin_huge_valf();
    const size_t outoff = ((size_t)b * T1_ + t0) * T2_;

#pragma unroll 1
    for (int i = 0; i < 4; ++i) {
        const int r = g + 8 * i;
        const float q2v = q2s[r];
        float M1 = NEG_INF;
#pragma unroll
        for (int m = 0; m < 16; ++m) {
            int t2 = (m >> 2) * 128 + xl * 4 + (m & 3);
            float raw = 1e-3f * acc[i][m] - 5e-4f * (q2v + k2s[t2]);
            acc[i][m] = raw;
            M1 = fmaxf(M1, raw);
        }
#pragma unroll
        for (int d = 1; d <= 16; d <<= 1) M1 = fmaxf(M1, __shfl_xor(M1, d, 64));
        float S1 = 0.f;
#pragma unroll
        for (int m = 0; m < 16; ++m) S1 += __expf(acc[i][m] - M1);
#pragma unroll
        for (int d = 1; d <= 16; d <<= 1) S1 += __shfl_xor(S1, d, 64);
        const float L1 = M1 + __logf(S1);

        const size_t rowbase = outoff + (size_t)r * T2_;
        const float* pr = prior + rowbase;
        float* o1 = out_logp + rowbase;
#pragma unroll
        for (int ch = 0; ch < 4; ++ch) {
            int t2b = ch * 128 + xl * 4;
            float4 pv = *(const float4*)&pr[t2b];
            float4 o;
            o.x = acc[i][ch * 4 + 0] - L1 + __logf(pv.x + 1e-8f);
            o.y = acc[i][ch * 4 + 1] - L1 + __logf(pv.y + 1e-8f);
            o.z = acc[i][ch * 4 + 2] - L1 + __logf(pv.z + 1e-8f);
            o.w = acc[i][ch * 4 + 3] - L1 + __logf(pv.w + 1e-8f);
            *(float4*)&o1[t2b] = o;
            acc[i][ch * 4 + 0] = o.x; acc[i][ch * 4 + 1] = o.y;
            acc[i][ch * 4 + 2] = o.z; acc[i][ch * 4 + 3] = o.w;
        }
        float M2 = NEG_INF;
#pragma unroll
        for (int m = 0; m < 16; ++m) {
            int t2 = (m >> 2) * 128 + xl * 4 + (m & 3);
            float am = msk[t2] ? NEG_INF : acc[i][m];
            acc[i][m] = am;
            M2 = fmaxf(M2, am);
        }
#pragma unroll
        for (int d = 1; d <= 16; d <<= 1) M2 = fmaxf(M2, __shfl_xor(M2, d, 64));
        float S2 = 0.f;
#pragma unroll
        for (int m = 0; m < 16; ++m) S2 += __expf(acc[i][m] - M2);
#pragma unroll
        for (int d = 1; d <= 16; d <<= 1) S2 += __shfl_xor(S2, d, 64);
        const float inv = 1.0f / S2;

        float* o0 = out_attn + rowbase;
#pragma unroll
        for (int ch = 0; ch < 4; ++ch) {
            int t2b = ch * 128 + xl * 4;
            float4 o;
            o.x = __expf(acc[i][ch * 4 + 0] - M2) * inv;
            o.y = __expf(acc[i][ch * 4 + 1] - M2) * inv;
            o.z = __expf(acc[i][ch * 4 + 2] - M2) * inv;
            o.w = __expf(acc[i][ch * 4 + 3] - M2) * inv;
            *(float4*)&o0[t2b] = o;
        }
    }
}

extern "C" void kernel_launch(void* const* d_in, const int* in_sizes, int n_in,
                              void* d_out, int out_size, void* d_ws, size_t ws_size,
                              hipStream_t stream)
{
    const float* queries = (const float*)d_in[0];
    const float* keys    = (const float*)d_in[1];
    const unsigned char* mask = (const unsigned char*)d_in[3];
    const float* prior   = (const float*)d_in[4];
    const float* kW1 = (const float*)d_in[5];
    const float* kb1 = (const float*)d_in[6];
    const float* kW2 = (const float*)d_in[7];
    const float* kb2 = (const float*)d_in[8];
    const float* qW1 = (const float*)d_in[9];
    const float* qb1 = (const float*)d_in[10];
    const float* qW2 = (const float*)d_in[11];
    const float* qb2 = (const float*)d_in[12];
    const float* qW3 = (const float*)d_in[13];
    const float* qb3 = (const float*)d_in[14];

    // workspace layout (ushort units):
    // R0 @ 0          : Bmat1 [32][512][1536] (25,165,824) / Bmat3 [32][2048][320] / Bmat5 [32][2048][128]
    // R1 @ 25,165,824 : Bmat2 [32][512][1024] (16,777,216) / Bmat4 [32][2048][256] / q_att [32][128][2048]
    // K  @ 41,943,040 : k_att [32][128][512]  (2,097,152)
    // W  @ 44,040,192 : padded bf16 weights   (1,835,008)
    // total 45,875,200 ushorts = 87.5 MiB
    unsigned short* ws = (unsigned short*)d_ws;
    unsigned short* Bmat1 = ws;
    unsigned short* Bmat3 = ws;
    unsigned short* Bmat5 = ws;
    unsigned short* Bmat2 = ws + 25165824;
    unsigned short* Bmat4 = ws + 25165824;
    unsigned short* q_att = ws + 25165824;
    unsigned short* k_att = ws + 41943040;
    unsigned short* Wk1b  = ws + 44040192;                // [1024][1536]
    unsigned short* Wk2b  = Wk1b + 1572864;               // [128][1024]
    unsigned short* Wq1b  = Wk2b + 131072;                // [256][320]
    unsigned short* Wq2b  = Wq1b + 81920;                 // [128][256]
    unsigned short* Wq3b  = Wq2b + 32768;                 // [128][128]

    float* out_attn = (float*)d_out;
    float* out_logp = (float*)d_out + (size_t)B_ * T1_ * T2_;

    dim3 blk(256);
    // weight casts
    cast_w<<<dim3((1024 * 1536 + 255) / 256), blk, 0, stream>>>(kW1, Wk1b, 1024, 1536, 1536, 1024);
    cast_w<<<dim3((128 * 1024 + 255) / 256), blk, 0, stream>>>(kW2, Wk2b, 100, 1024, 1024, 128);
    cast_w<<<dim3((256 * 320 + 255) / 256), blk, 0, stream>>>(qW1, Wq1b, 200, 300, 320, 256);
    cast_w<<<dim3((128 * 256 + 255) / 256), blk, 0, stream>>>(qW2, Wq2b, 100, 200, 256, 128);
    cast_w<<<dim3((128 * 128 + 255) / 256), blk, 0, stream>>>(qW3, Wq3b, 100, 100, 128, 128);
    // key path
    im2col_k3<<<dim3(512 * 1536 / 256, B_), blk, 0, stream>>>(keys, Bmat1, 512, T2_, 1536);
    gemm_conv<1, 1><<<dim3(4, 8, B_), blk, 0, stream>>>(Wk1b, Bmat1, kb1, Bmat2, 1024, 1536, T2_, 1024);
    gemm_conv<0, 0><<<dim3(4, 1, B_), blk, 0, stream>>>(Wk2b, Bmat2, kb2, k_att, 100, 1024, T2_, 128);
    // query path
    im2col_k3<<<dim3(2048 * 320 / 256, B_), blk, 0, stream>>>(queries, Bmat3, 100, T1_, 320);
    gemm_conv<1, 1><<<dim3(16, 2, B_), blk, 0, stream>>>(Wq1b, Bmat3, qb1, Bmat4, 200, 320, T1_, 256);
    gemm_conv<1, 1><<<dim3(16, 1, B_), blk, 0, stream>>>(Wq2b, Bmat4, qb2, Bmat5, 100, 256, T1_, 128);
    gemm_conv<0, 0><<<dim3(16, 1, B_), blk, 0, stream>>>(Wq3b, Bmat5, qb3, q_att, 100, 128, T1_, 128);
    // attention
    attn_kernel<<<dim3(T1_ / 32, B_), blk, 0, stream>>>(q_att, k_att, mask, prior, out_attn, out_logp);

    (void)in_sizes; (void)n_in; (void)out_size; (void)ws_size;
}

// Round 3
// 761.814 us; speedup vs baseline: 2.7223x; 1.2906x over previous
//
#include <hip/hip_runtime.h>
#include <cstdint>

#define B_   32
#define T1_  2048
#define T2_  512

typedef __attribute__((ext_vector_type(8))) short short8;   // 8 x bf16 (4 VGPRs)
typedef __attribute__((ext_vector_type(4))) float f32x4;

__device__ __forceinline__ unsigned short f2bf(float f) {
    union { float f; unsigned u; } x; x.f = f;
    unsigned r = x.u + 0x7fffu + ((x.u >> 16) & 1u);   // RNE
    return (unsigned short)(r >> 16);
}
__device__ __forceinline__ float bf2f(unsigned short u) {
    union { unsigned u; float f; } x; x.u = ((unsigned)u) << 16;
    return x.f;
}

__device__ __forceinline__ void async16(const unsigned short* g, unsigned short* l) {
    __builtin_amdgcn_global_load_lds(
        (const __attribute__((address_space(1))) unsigned int*)g,
        (__attribute__((address_space(3))) unsigned int*)l, 16, 0, 0);
}

// ---------------------------------------------------------------------------
// Weight cast+pad: W fp32 [Cout][CK] -> Wb bf16 [Mpad][CKp], zero padding.
// ---------------------------------------------------------------------------
__global__ void cast_w(const float* __restrict__ W, unsigned short* __restrict__ Wb,
                       int Cout, int CK, int CKp, int Mpad)
{
    int idx = blockIdx.x * 256 + threadIdx.x;
    if (idx >= Mpad * CKp) return;
    int m = idx / CKp, c = idx - m * CKp;
    float v = (m < Cout && c < CK) ? W[(size_t)m * CK + c] : 0.f;
    Wb[idx] = f2bf(v);
}

// ---------------------------------------------------------------------------
// im2col for k=3, pad=1 (compile-time divisors -> magic-mul, no v_rcp chains)
// ---------------------------------------------------------------------------
template<int CIN, int CKP>
__global__ void im2col_k3(const float* __restrict__ X, unsigned short* __restrict__ Bmat,
                          int T)
{
    int b = blockIdx.y;
    int idx = blockIdx.x * 256 + threadIdx.x;
    if (idx >= T * CKP) return;
    int t = idx / CKP, c = idx - t * CKP;
    constexpr int CK = CIN * 3;
    float v = 0.f;
    if (c < CK) {
        int ci = c / 3, dk = c - ci * 3;
        int ts = t + dk - 1;
        if (ts >= 0 && ts < T) v = X[((size_t)b * CIN + ci) * T + ts];
    }
    Bmat[(size_t)b * T * CKP + idx] = f2bf(v);
}

// ---------------------------------------------------------------------------
// bf16 MFMA GEMM (m97 structure), unchanged from round 2 (passed).
// TRANS=1: Y as [b][t][Mpad] bf16 ; TRANS=0: Y as [b][Mpad][t] bf16.
// ---------------------------------------------------------------------------
template<int TRANS, int RELU>
__global__ __launch_bounds__(256) void gemm_conv(
    const unsigned short* __restrict__ A,   // [Mpad][CK] bf16 weights (padded)
    const unsigned short* __restrict__ Bm,  // [B][N][CK] bf16 im2col
    const float* __restrict__ bias,         // [Cout] fp32
    unsigned short* __restrict__ Y,
    int Cout, int CK, int N, int Mpad)
{
    __shared__ __align__(16) unsigned char smem[35328];
    unsigned short* Al = (unsigned short*)smem;          // [128][32]
    unsigned short* Bl = Al + 4096;                      // [128][32]
    unsigned short* Ct = (unsigned short*)smem;          // [128][136] epilogue
    float* biasS = (float*)(smem + 34816);               // [128]

    const int b   = blockIdx.z;
    const int co0 = blockIdx.y * 128;
    const int t0  = blockIdx.x * 128;
    const int tid = threadIdx.x;
    const int wave = tid >> 6, lane = tid & 63;
    const int lm = lane & 15, kg = lane >> 4;
    const int mbase = (wave >> 1) * 64, nbase = (wave & 1) * 64;

    if (tid < 128) biasS[tid] = (co0 + tid < Cout) ? bias[co0 + tid] : 0.f;

    const unsigned short* Ab = A + (size_t)co0 * CK;
    const unsigned short* Bb = Bm + ((size_t)b * N + t0) * CK;
    const int rL = lane >> 2;
    const int cA = (lane & 3) * 8;

    f32x4 acc[4][4];
#pragma unroll
    for (int mi = 0; mi < 4; ++mi)
#pragma unroll
        for (int ni = 0; ni < 4; ++ni) acc[mi][ni] = (f32x4){0.f, 0.f, 0.f, 0.f};

    for (int kk = 0; kk < CK; kk += 32) {
        __syncthreads();
#pragma unroll
        for (int i = 0; i < 2; ++i) {
            int R0 = i * 64 + wave * 16;
            async16(Ab + (size_t)(R0 + rL) * CK + kk + cA, Al + R0 * 32);
            async16(Bb + (size_t)(R0 + rL) * CK + kk + cA, Bl + R0 * 32);
        }
        __syncthreads();
        short8 av[4], bv[4];
#pragma unroll
        for (int mi = 0; mi < 4; ++mi)
            av[mi] = *(const short8*)(Al + (mbase + mi * 16 + lm) * 32 + kg * 8);
#pragma unroll
        for (int ni = 0; ni < 4; ++ni)
            bv[ni] = *(const short8*)(Bl + (nbase + ni * 16 + lm) * 32 + kg * 8);
#pragma unroll
        for (int mi = 0; mi < 4; ++mi)
#pragma unroll
            for (int ni = 0; ni < 4; ++ni)
                acc[mi][ni] = __builtin_amdgcn_mfma_f32_16x16x32_bf16(
                    av[mi], bv[ni], acc[mi][ni], 0, 0, 0);
    }
    __syncthreads();

    if (TRANS) {
#pragma unroll
        for (int mi = 0; mi < 4; ++mi)
#pragma unroll
            for (int ni = 0; ni < 4; ++ni)
#pragma unroll
                for (int r = 0; r < 4; ++r) {
                    int co_l = mbase + mi * 16 + kg * 4 + r;
                    int t_l  = nbase + ni * 16 + lm;
                    float v = acc[mi][ni][r] + biasS[co_l];
                    if (RELU) v = fmaxf(v, 0.f);
                    Ct[t_l * 136 + co_l] = f2bf(v);
                }
        __syncthreads();
        unsigned short* Yb = Y + ((size_t)b * N + t0) * Mpad + co0;
        int c0 = (tid & 15) * 8;
#pragma unroll
        for (int p = 0; p < 8; ++p) {
            int r = (tid >> 4) + p * 16;
            *(uint4*)(Yb + (size_t)r * Mpad + c0) = *(const uint4*)(Ct + r * 136 + c0);
        }
    } else {
#pragma unroll
        for (int mi = 0; mi < 4; ++mi)
#pragma unroll
            for (int ni = 0; ni < 4; ++ni)
#pragma unroll
                for (int r = 0; r < 4; ++r) {
                    int co_l = mbase + mi * 16 + kg * 4 + r;
                    int t_l  = nbase + ni * 16 + lm;
                    float v = acc[mi][ni][r] + biasS[co_l];
                    if (RELU) v = fmaxf(v, 0.f);
                    Y[((size_t)b * Mpad + co0 + co_l) * N + t0 + t_l] = f2bf(v);
                }
    }
}

// ---------------------------------------------------------------------------
// Squared norms of 128-wide bf16 rows: first 65536 rows = q, next 16384 = k.
// One 16-lane group per row.
// ---------------------------------------------------------------------------
__global__ __launch_bounds__(256) void norms_kernel(
    const unsigned short* __restrict__ q, const unsigned short* __restrict__ k,
    float* __restrict__ q2, float* __restrict__ k2)
{
    int row = blockIdx.x * 16 + (threadIdx.x >> 4);
    int l = threadIdx.x & 15;
    const unsigned short* src;
    float* dst;
    if (row < 65536) { src = q + (size_t)row * 128; dst = q2 + row; }
    else             { src = k + (size_t)(row - 65536) * 128; dst = k2 + (row - 65536); }
    short8 v = *(const short8*)(src + l * 8);
    float s = 0.f;
#pragma unroll
    for (int j = 0; j < 8; ++j) { float f = bf2f((unsigned short)v[j]); s += f * f; }
#pragma unroll
    for (int d = 1; d <= 8; d <<= 1) s += __shfl_xor(s, d, 64);
    if (l == 0) *dst = s;
}

// ---------------------------------------------------------------------------
// MFMA attention. Block = (b, 32 q-rows) x all 512 cols; 4 waves, wave w owns
// cols [128w,128w+128). A/B frags loaded straight from global (L2-resident),
// no LDS staging. acc[2][8] f32x4, all statically indexed (register-resident).
// C layout: row = quad*4+reg (+16*mi), col = lm (+16*nf + 128*wave).
// Softmax: in-lane over nf -> shfl over 16 lanes -> LDS cross-wave combine.
// ---------------------------------------------------------------------------
__global__ __launch_bounds__(256) void attn_mfma(
    const unsigned short* __restrict__ q,   // [B*T1][128] bf16 (rows >=100 zero)
    const unsigned short* __restrict__ k,   // [B*T2][128] bf16
    const float* __restrict__ q2,           // [B*T1]
    const float* __restrict__ k2,           // [B*T2]
    const unsigned char* __restrict__ mask, // [B*T2]
    const float* __restrict__ prior,        // [B,T1,T2]
    float* __restrict__ out_attn, float* __restrict__ out_logp)
{
    __shared__ float redM[4][32], redS[4][32];
    __shared__ float rowA[32], rowB[32];

    const int b = blockIdx.y, t0 = blockIdx.x * 32;
    const int tid = threadIdx.x, wave = tid >> 6, lane = tid & 63;
    const int lm = lane & 15, quad = lane >> 4;
    const float NEG_INF = -__builtin_huge_valf();

    // A fragments (q rows t0..t0+31, K=128)
    const unsigned short* qb = q + ((size_t)b * T1_ + t0) * 128;
    short8 af[2][4];
#pragma unroll
    for (int mi = 0; mi < 2; ++mi)
#pragma unroll
        for (int kb = 0; kb < 4; ++kb)
            af[mi][kb] = *(const short8*)(qb + (size_t)(mi * 16 + lm) * 128 + kb * 32 + quad * 8);

    // qk via MFMA
    f32x4 acc[2][8];
#pragma unroll
    for (int mi = 0; mi < 2; ++mi)
#pragma unroll
        for (int nf = 0; nf < 8; ++nf) acc[mi][nf] = (f32x4){0.f, 0.f, 0.f, 0.f};

    const unsigned short* kp = k + ((size_t)b * T2_ + wave * 128) * 128;
#pragma unroll
    for (int nf = 0; nf < 8; ++nf) {
        short8 bfr[4];
#pragma unroll
        for (int kb = 0; kb < 4; ++kb)
            bfr[kb] = *(const short8*)(kp + (size_t)(nf * 16 + lm) * 128 + kb * 32 + quad * 8);
#pragma unroll
        for (int mi = 0; mi < 2; ++mi)
#pragma unroll
            for (int kb = 0; kb < 4; ++kb)
                acc[mi][nf] = __builtin_amdgcn_mfma_f32_16x16x32_bf16(
                    af[mi][kb], bfr[kb], acc[mi][nf], 0, 0, 0);
    }

    // raw logits: 1e-3*qk - 5e-4*(|q|^2 + |k|^2)
    float k2v[8];
    unsigned char mk[8];
#pragma unroll
    for (int nf = 0; nf < 8; ++nf) {
        int col = wave * 128 + nf * 16 + lm;
        k2v[nf] = k2[b * T2_ + col];
        mk[nf]  = mask[b * T2_ + col];
    }
    float q2v[2][4];
#pragma unroll
    for (int mi = 0; mi < 2; ++mi)
#pragma unroll
        for (int r = 0; r < 4; ++r)
            q2v[mi][r] = q2[b * T1_ + t0 + mi * 16 + quad * 4 + r];
#pragma unroll
    for (int mi = 0; mi < 2; ++mi)
#pragma unroll
        for (int nf = 0; nf < 8; ++nf)
#pragma unroll
            for (int r = 0; r < 4; ++r)
                acc[mi][nf][r] = 1e-3f * acc[mi][nf][r] - 5e-4f * (q2v[mi][r] + k2v[nf]);

    // pass 1: per-wave (M1,S1) over 128 cols, then cross-wave combine -> L1
#pragma unroll
    for (int mi = 0; mi < 2; ++mi)
#pragma unroll
        for (int r = 0; r < 4; ++r) {
            float m = NEG_INF;
#pragma unroll
            for (int nf = 0; nf < 8; ++nf) m = fmaxf(m, acc[mi][nf][r]);
#pragma unroll
            for (int d = 1; d <= 8; d <<= 1) m = fmaxf(m, __shfl_xor(m, d, 64));
            float s = 0.f;
#pragma unroll
            for (int nf = 0; nf < 8; ++nf) s += __expf(acc[mi][nf][r] - m);
#pragma unroll
            for (int d = 1; d <= 8; d <<= 1) s += __shfl_xor(s, d, 64);
            if (lm == 0) {
                redM[wave][mi * 16 + quad * 4 + r] = m;
                redS[wave][mi * 16 + quad * 4 + r] = s;
            }
        }
    __syncthreads();
    if (tid < 32) {
        float m = redM[0][tid];
        m = fmaxf(m, redM[1][tid]); m = fmaxf(m, redM[2][tid]); m = fmaxf(m, redM[3][tid]);
        float s = 0.f;
#pragma unroll
        for (int w = 0; w < 4; ++w) s += redS[w][tid] * __expf(redM[w][tid] - m);
        rowA[tid] = m + __logf(s);   // L1
    }
    __syncthreads();
    float L1[2][4];
#pragma unroll
    for (int mi = 0; mi < 2; ++mi)
#pragma unroll
        for (int r = 0; r < 4; ++r) L1[mi][r] = rowA[mi * 16 + quad * 4 + r];

    // pass 1.5: t = raw + log(prior); store logp = t - L1 ; mask -> -inf
    const size_t base = ((size_t)b * T1_ + t0) * T2_;
#pragma unroll
    for (int mi = 0; mi < 2; ++mi)
#pragma unroll
        for (int r = 0; r < 4; ++r) {
            size_t rowoff = base + (size_t)(mi * 16 + quad * 4 + r) * T2_;
#pragma unroll
            for (int nf = 0; nf < 8; ++nf) {
                int col = wave * 128 + nf * 16 + lm;
                float pv = prior[rowoff + col];
                float t = acc[mi][nf][r] + __logf(pv + 1e-8f);
                out_logp[rowoff + col] = t - L1[mi][r];
                acc[mi][nf][r] = mk[nf] ? NEG_INF : t;
            }
        }

    // pass 2: masked softmax stats
#pragma unroll
    for (int mi = 0; mi < 2; ++mi)
#pragma unroll
        for (int r = 0; r < 4; ++r) {
            float m = NEG_INF;
#pragma unroll
            for (int nf = 0; nf < 8; ++nf) m = fmaxf(m, acc[mi][nf][r]);
#pragma unroll
            for (int d = 1; d <= 8; d <<= 1) m = fmaxf(m, __shfl_xor(m, d, 64));
            float s = 0.f;
#pragma unroll
            for (int nf = 0; nf < 8; ++nf) s += __expf(acc[mi][nf][r] - m);
#pragma unroll
            for (int d = 1; d <= 8; d <<= 1) s += __shfl_xor(s, d, 64);
            if (lm == 0) {
                redM[wave][mi * 16 + quad * 4 + r] = m;
                redS[wave][mi * 16 + quad * 4 + r] = s;
            }
        }
    __syncthreads();
    if (tid < 32) {
        float m = redM[0][tid];
        m = fmaxf(m, redM[1][tid]); m = fmaxf(m, redM[2][tid]); m = fmaxf(m, redM[3][tid]);
        float s = 0.f;
#pragma unroll
        for (int w = 0; w < 4; ++w) s += redS[w][tid] * __expf(redM[w][tid] - m);
        rowA[tid] = m;
        rowB[tid] = 1.0f / s;
    }
    __syncthreads();

#pragma unroll
    for (int mi = 0; mi < 2; ++mi)
#pragma unroll
        for (int r = 0; r < 4; ++r) {
            int rl = mi * 16 + quad * 4 + r;
            float m2 = rowA[rl], is2 = rowB[rl];
            size_t rowoff = base + (size_t)rl * T2_;
#pragma unroll
            for (int nf = 0; nf < 8; ++nf) {
                int col = wave * 128 + nf * 16 + lm;
                out_attn[rowoff + col] = __expf(acc[mi][nf][r] - m2) * is2;
            }
        }
}

extern "C" void kernel_launch(void* const* d_in, const int* in_sizes, int n_in,
                              void* d_out, int out_size, void* d_ws, size_t ws_size,
                              hipStream_t stream)
{
    const float* queries = (const float*)d_in[0];
    const float* keys    = (const float*)d_in[1];
    const unsigned char* mask = (const unsigned char*)d_in[3];
    const float* prior   = (const float*)d_in[4];
    const float* kW1 = (const float*)d_in[5];
    const float* kb1 = (const float*)d_in[6];
    const float* kW2 = (const float*)d_in[7];
    const float* kb2 = (const float*)d_in[8];
    const float* qW1 = (const float*)d_in[9];
    const float* qb1 = (const float*)d_in[10];
    const float* qW2 = (const float*)d_in[11];
    const float* qb2 = (const float*)d_in[12];
    const float* qW3 = (const float*)d_in[13];
    const float* qb3 = (const float*)d_in[14];

    // workspace layout (ushort units):
    // R0 @ 0          : Bmat1 [32][512][1536] / Bmat3 [32][2048][320] / Bmat5 [32][2048][128]
    // R1 @ 25,165,824 : Bmat2 [32][512][1024] / Bmat4 [32][2048][256] / q_att [32][2048][128]
    // K  @ 41,943,040 : k_att [32][512][128]
    // W  @ 44,040,192 : padded bf16 weights (1,835,008)
    // N  @ 45,875,200 : q2 [65536] f32 (131072 ushorts) ; k2 [16384] f32 (32768)
    unsigned short* ws = (unsigned short*)d_ws;
    unsigned short* Bmat1 = ws;
    unsigned short* Bmat3 = ws;
    unsigned short* Bmat5 = ws;
    unsigned short* Bmat2 = ws + 25165824;
    unsigned short* Bmat4 = ws + 25165824;
    unsigned short* q_att = ws + 25165824;
    unsigned short* k_att = ws + 41943040;
    unsigned short* Wk1b  = ws + 44040192;                // [1024][1536]
    unsigned short* Wk2b  = Wk1b + 1572864;               // [128][1024]
    unsigned short* Wq1b  = Wk2b + 131072;                // [256][320]
    unsigned short* Wq2b  = Wq1b + 81920;                 // [128][256]
    unsigned short* Wq3b  = Wq2b + 32768;                 // [128][128]
    float* q2f = (float*)(ws + 45875200);
    float* k2f = q2f + 65536;

    float* out_attn = (float*)d_out;
    float* out_logp = (float*)d_out + (size_t)B_ * T1_ * T2_;

    dim3 blk(256);
    cast_w<<<dim3((1024 * 1536 + 255) / 256), blk, 0, stream>>>(kW1, Wk1b, 1024, 1536, 1536, 1024);
    cast_w<<<dim3((128 * 1024 + 255) / 256), blk, 0, stream>>>(kW2, Wk2b, 100, 1024, 1024, 128);
    cast_w<<<dim3((256 * 320 + 255) / 256), blk, 0, stream>>>(qW1, Wq1b, 200, 300, 320, 256);
    cast_w<<<dim3((128 * 256 + 255) / 256), blk, 0, stream>>>(qW2, Wq2b, 100, 200, 256, 128);
    cast_w<<<dim3((128 * 128 + 255) / 256), blk, 0, stream>>>(qW3, Wq3b, 100, 100, 128, 128);
    // key path -> k_att [b][512][128]
    im2col_k3<512, 1536><<<dim3(512 * 1536 / 256, B_), blk, 0, stream>>>(keys, Bmat1, T2_);
    gemm_conv<1, 1><<<dim3(4, 8, B_), blk, 0, stream>>>(Wk1b, Bmat1, kb1, Bmat2, 1024, 1536, T2_, 1024);
    gemm_conv<1, 0><<<dim3(4, 1, B_), blk, 0, stream>>>(Wk2b, Bmat2, kb2, k_att, 100, 1024, T2_, 128);
    // query path -> q_att [b][2048][128]
    im2col_k3<100, 320><<<dim3(2048 * 320 / 256, B_), blk, 0, stream>>>(queries, Bmat3, T1_);
    gemm_conv<1, 1><<<dim3(16, 2, B_), blk, 0, stream>>>(Wq1b, Bmat3, qb1, Bmat4, 200, 320, T1_, 256);
    gemm_conv<1, 1><<<dim3(16, 1, B_), blk, 0, stream>>>(Wq2b, Bmat4, qb2, Bmat5, 100, 256, T1_, 128);
    gemm_conv<1, 0><<<dim3(16, 1, B_), blk, 0, stream>>>(Wq3b, Bmat5, qb3, q_att, 100, 128, T1_, 128);
    // norms + attention
    norms_kernel<<<dim3((65536 + 16384) / 16), blk, 0, stream>>>(q_att, k_att, q2f, k2f);
    attn_mfma<<<dim3(T1_ / 32, B_), blk, 0, stream>>>(q_att, k_att, q2f, k2f, mask, prior, out_attn, out_logp);

    (void)in_sizes; (void)n_in; (void)out_size; (void)ws_size;
}

// Round 4
// 615.616 us; speedup vs baseline: 3.3688x; 1.2375x over previous
//
#include <hip/hip_runtime.h>
#include <cstdint>

#define B_   32
#define T1_  2048
#define T2_  512

typedef __attribute__((ext_vector_type(8))) short short8;   // 8 x bf16 (4 VGPRs)
typedef __attribute__((ext_vector_type(4))) float f32x4;

__device__ __forceinline__ unsigned short f2bf(float f) {
    union { float f; unsigned u; } x; x.f = f;
    unsigned r = x.u + 0x7fffu + ((x.u >> 16) & 1u);   // RNE
    return (unsigned short)(r >> 16);
}
__device__ __forceinline__ float bf2f(unsigned short u) {
    union { unsigned u; float f; } x; x.u = ((unsigned)u) << 16;
    return x.f;
}

__device__ __forceinline__ void async16(const unsigned short* g, unsigned short* l) {
    __builtin_amdgcn_global_load_lds(
        (const __attribute__((address_space(1))) unsigned int*)g,
        (__attribute__((address_space(3))) unsigned int*)l, 16, 0, 0);
}

// ---------------------------------------------------------------------------
// prep: (a) transpose-cast keys -> keysT [32][514][512] bf16 (rows t=-1,T zero)
//       (b) transpose-cast queries -> queriesT [32][2050][128] bf16
//       (c) all 5 weight casts into one contiguous bf16 region:
//           Wk1s[3][1024][512] | Wk2[128][1024] | Wq1s[3][256][128] |
//           Wq2[128][256] | Wq3[128][128]
// Blocks: [0,8192) keys tiles, [8192,16384) queries tiles, [16384,17408) weights
// ---------------------------------------------------------------------------
__global__ __launch_bounds__(256) void prep_kernel(
    const float* __restrict__ queries, const float* __restrict__ keys,
    const float* __restrict__ kW1, const float* __restrict__ kW2,
    const float* __restrict__ qW1, const float* __restrict__ qW2,
    const float* __restrict__ qW3,
    unsigned short* __restrict__ keysT, unsigned short* __restrict__ queriesT,
    unsigned short* __restrict__ Wdst)
{
    __shared__ float tile[32][33];
    const int blk = blockIdx.x, tid = threadIdx.x;
    if (blk < 16384) {
        const float* X; unsigned short* Y; int C, Cp, T, ntx, tx, ty, b;
        if (blk < 8192) {
            X = keys; Y = keysT; C = 512; Cp = 512; T = 512; ntx = 16;
            b = blk >> 8; int rem = blk & 255; ty = rem >> 4; tx = rem & 15;
        } else {
            int f = blk - 8192;
            X = queries; Y = queriesT; C = 100; Cp = 128; T = 2048; ntx = 64;
            b = f >> 8; int rem = f & 255; tx = rem >> 2; ty = rem & 3;
        }
        const int c0 = ty * 32, t0 = tx * 32;
        const int cl = tid >> 5, tl = tid & 31;
#pragma unroll
        for (int i = 0; i < 4; ++i) {
            int c = c0 + cl + i * 8;
            float v = (c < C) ? X[((size_t)b * C + c) * T + t0 + tl] : 0.f;
            tile[cl + i * 8][tl] = v;
        }
        __syncthreads();
#pragma unroll
        for (int i = 0; i < 4; ++i) {
            int tw = cl + i * 8, cw = tl;
            Y[((size_t)b * (T + 2) + t0 + tw + 1) * Cp + c0 + cw] = f2bf(tile[cw][tw]);
        }
        if (tid < 32) {
            if (tx == 0)       Y[((size_t)b * (T + 2)) * Cp + c0 + tid] = 0;
            if (tx == ntx - 1) Y[((size_t)b * (T + 2) + T + 1) * Cp + c0 + tid] = 0;
        }
    } else {
        size_t base = (size_t)(blk - 16384) * 2048 + (size_t)tid * 8;
#pragma unroll
        for (int j = 0; j < 8; ++j) {
            size_t idx = base + j;
            float v = 0.f;
            if (idx < 1572864) {                  // Wk1s [3][1024][512]
                int dk = (int)(idx / 524288); int rem = (int)(idx % 524288);
                int m = rem >> 9, ci = rem & 511;
                v = kW1[((size_t)m * 512 + ci) * 3 + dk];
            } else if (idx < 1703936) {           // Wk2 [128][1024]
                int r = (int)(idx - 1572864); int m = r >> 10, c = r & 1023;
                if (m < 100) v = kW2[(size_t)m * 1024 + c];
            } else if (idx < 1802240) {           // Wq1s [3][256][128]
                int r = (int)(idx - 1703936); int dk = r / 32768, rem = r % 32768;
                int m = rem >> 7, ci = rem & 127;
                if (m < 200 && ci < 100) v = qW1[((size_t)m * 100 + ci) * 3 + dk];
            } else if (idx < 1835008) {           // Wq2 [128][256]
                int r = (int)(idx - 1802240); int m = r >> 8, c = r & 255;
                if (m < 100 && c < 200) v = qW2[(size_t)m * 200 + c];
            } else if (idx < 1851392) {           // Wq3 [128][128]
                int r = (int)(idx - 1835008); int m = r >> 7, c = r & 127;
                if (m < 100 && c < 100) v = qW3[(size_t)m * 100 + c];
            } else {
                continue;
            }
            Wdst[idx] = f2bf(v);
        }
    }
}

// ---------------------------------------------------------------------------
// Paired bf16 MFMA conv-GEMM. KW=3: B is [b][N+2][Ck] (row 0 = t=-1), conv
// realized as 3 accumulating GEMM passes over shifted row windows; A is
// [KW][Mpad][Ck]. KW=1: plain GEMM, B [b][N][Ck]. Always writes Y transposed
// as [b][N][Mpad] bf16 via LDS-staged epilogue. Optional fused row-norms
// (requires Mpad==128). Two independent GEMMs per launch (flat-grid split).
// ---------------------------------------------------------------------------
struct GArgs {
    const unsigned short* A;
    const unsigned short* Bm;
    const float* bias;
    unsigned short* Y;
    float* nrm;
    int Ck, N, Mpad, nx, relu, norm, Cout;
};

template<int KW>
__global__ __launch_bounds__(256) void gemm_pair(GArgs g0, GArgs g1, int n0)
{
    __shared__ __align__(16) unsigned char smem[36352];
    unsigned short* Al = (unsigned short*)smem;           // [128][32]
    unsigned short* Bl = Al + 4096;                       // [128][32]
    unsigned short* Ct = (unsigned short*)smem;           // [128][136] epilogue
    float* biasS = (float*)(smem + 34816);                // [128]
    float* normS = (float*)(smem + 35328);                // [2][128]

    const bool first = (blockIdx.x < (unsigned)n0);
    const GArgs g = first ? g0 : g1;
    const int idx = first ? blockIdx.x : (blockIdx.x - n0);
    const int ny = g.Mpad >> 7;
    const int per_b = g.nx * ny;
    const int b = idx / per_b; const int rem = idx - b * per_b;
    const int y = rem / g.nx, x = rem - y * g.nx;
    const int co0 = y * 128, t0 = x * 128;

    const int tid = threadIdx.x;
    const int wave = tid >> 6, lane = tid & 63;
    const int lm = lane & 15, kg = lane >> 4;
    const int mbase = (wave >> 1) * 64, nbase = (wave & 1) * 64;

    if (tid < 128) biasS[tid] = (co0 + tid < g.Cout) ? g.bias[co0 + tid] : 0.f;

    const int rL = lane >> 2;
    const int cA = (lane & 3) * 8;
    const int Ck = g.Ck;

    f32x4 acc[4][4];
#pragma unroll
    for (int mi = 0; mi < 4; ++mi)
#pragma unroll
        for (int ni = 0; ni < 4; ++ni) acc[mi][ni] = (f32x4){0.f, 0.f, 0.f, 0.f};

#pragma unroll 1
    for (int dk = 0; dk < KW; ++dk) {
        const unsigned short* Ad = g.A + ((size_t)dk * g.Mpad + co0) * Ck;
        const unsigned short* Bd = g.Bm +
            ((size_t)b * (g.N + (KW == 3 ? 2 : 0)) + t0 + dk) * Ck;
        for (int kk = 0; kk < Ck; kk += 32) {
            __syncthreads();
#pragma unroll
            for (int i = 0; i < 2; ++i) {
                int R0 = i * 64 + wave * 16;   // wave-uniform
                async16(Ad + (size_t)(R0 + rL) * Ck + kk + cA, Al + R0 * 32);
                async16(Bd + (size_t)(R0 + rL) * Ck + kk + cA, Bl + R0 * 32);
            }
            __syncthreads();
            short8 av[4], bv[4];
#pragma unroll
            for (int mi = 0; mi < 4; ++mi)
                av[mi] = *(const short8*)(Al + (mbase + mi * 16 + lm) * 32 + kg * 8);
#pragma unroll
            for (int ni = 0; ni < 4; ++ni)
                bv[ni] = *(const short8*)(Bl + (nbase + ni * 16 + lm) * 32 + kg * 8);
#pragma unroll
            for (int mi = 0; mi < 4; ++mi)
#pragma unroll
                for (int ni = 0; ni < 4; ++ni)
                    acc[mi][ni] = __builtin_amdgcn_mfma_f32_16x16x32_bf16(
                        av[mi], bv[ni], acc[mi][ni], 0, 0, 0);
        }
    }
    __syncthreads();

    // epilogue: bias(+relu), stage transposed bf16 tile, fused row-norms
    float sq[4] = {0.f, 0.f, 0.f, 0.f};
#pragma unroll
    for (int mi = 0; mi < 4; ++mi)
#pragma unroll
        for (int ni = 0; ni < 4; ++ni)
#pragma unroll
            for (int r = 0; r < 4; ++r) {
                int co_l = mbase + mi * 16 + kg * 4 + r;
                int t_l  = nbase + ni * 16 + lm;
                float v = acc[mi][ni][r] + biasS[co_l];
                if (g.relu) v = fmaxf(v, 0.f);
                Ct[t_l * 136 + co_l] = f2bf(v);
                sq[ni] += v * v;
            }
    if (g.norm) {
#pragma unroll
        for (int ni = 0; ni < 4; ++ni) {
            float s = sq[ni];
            s += __shfl_xor(s, 16, 64);
            s += __shfl_xor(s, 32, 64);
            if (kg == 0) normS[(wave >> 1) * 128 + nbase + ni * 16 + lm] = s;
        }
    }
    __syncthreads();
    unsigned short* Yb = g.Y + ((size_t)b * g.N + t0) * g.Mpad + co0;
    int c0 = (tid & 15) * 8;
#pragma unroll
    for (int p = 0; p < 8; ++p) {
        int r = (tid >> 4) + p * 16;
        *(uint4*)(Yb + (size_t)r * g.Mpad + c0) = *(const uint4*)(Ct + r * 136 + c0);
    }
    if (g.norm && tid < 128)
        g.nrm[(size_t)b * g.N + t0 + tid] = normS[tid] + normS[128 + tid];
}

// ---------------------------------------------------------------------------
// MFMA attention (unchanged from round 3 — passed). Block = (b, 32 q-rows) x
// all 512 cols; wave w owns cols [128w,128w+128); frags straight from L2.
// ---------------------------------------------------------------------------
__global__ __launch_bounds__(256) void attn_mfma(
    const unsigned short* __restrict__ q,   // [B*T1][128] bf16
    const unsigned short* __restrict__ k,   // [B*T2][128] bf16
    const float* __restrict__ q2,           // [B*T1]
    const float* __restrict__ k2,           // [B*T2]
    const unsigned char* __restrict__ mask, // [B*T2]
    const float* __restrict__ prior,        // [B,T1,T2]
    float* __restrict__ out_attn, float* __restrict__ out_logp)
{
    __shared__ float redM[4][32], redS[4][32];
    __shared__ float rowA[32], rowB[32];

    const int b = blockIdx.y, t0 = blockIdx.x * 32;
    const int tid = threadIdx.x, wave = tid >> 6, lane = tid & 63;
    const int lm = lane & 15, quad = lane >> 4;
    const float NEG_INF = -__builtin_huge_valf();

    const unsigned short* qb = q + ((size_t)b * T1_ + t0) * 128;
    short8 af[2][4];
#pragma unroll
    for (int mi = 0; mi < 2; ++mi)
#pragma unroll
        for (int kb = 0; kb < 4; ++kb)
            af[mi][kb] = *(const short8*)(qb + (size_t)(mi * 16 + lm) * 128 + kb * 32 + quad * 8);

    f32x4 acc[2][8];
#pragma unroll
    for (int mi = 0; mi < 2; ++mi)
#pragma unroll
        for (int nf = 0; nf < 8; ++nf) acc[mi][nf] = (f32x4){0.f, 0.f, 0.f, 0.f};

    const unsigned short* kp = k + ((size_t)b * T2_ + wave * 128) * 128;
#pragma unroll
    for (int nf = 0; nf < 8; ++nf) {
        short8 bfr[4];
#pragma unroll
        for (int kb = 0; kb < 4; ++kb)
            bfr[kb] = *(const short8*)(kp + (size_t)(nf * 16 + lm) * 128 + kb * 32 + quad * 8);
#pragma unroll
        for (int mi = 0; mi < 2; ++mi)
#pragma unroll
            for (int kb = 0; kb < 4; ++kb)
                acc[mi][nf] = __builtin_amdgcn_mfma_f32_16x16x32_bf16(
                    af[mi][kb], bfr[kb], acc[mi][nf], 0, 0, 0);
    }

    float k2v[8];
    unsigned char mk[8];
#pragma unroll
    for (int nf = 0; nf < 8; ++nf) {
        int col = wave * 128 + nf * 16 + lm;
        k2v[nf] = k2[b * T2_ + col];
        mk[nf]  = mask[b * T2_ + col];
    }
    float q2v[2][4];
#pragma unroll
    for (int mi = 0; mi < 2; ++mi)
#pragma unroll
        for (int r = 0; r < 4; ++r)
            q2v[mi][r] = q2[b * T1_ + t0 + mi * 16 + quad * 4 + r];
#pragma unroll
    for (int mi = 0; mi < 2; ++mi)
#pragma unroll
        for (int nf = 0; nf < 8; ++nf)
#pragma unroll
            for (int r = 0; r < 4; ++r)
                acc[mi][nf][r] = 1e-3f * acc[mi][nf][r] - 5e-4f * (q2v[mi][r] + k2v[nf]);

#pragma unroll
    for (int mi = 0; mi < 2; ++mi)
#pragma unroll
        for (int r = 0; r < 4; ++r) {
            float m = NEG_INF;
#pragma unroll
            for (int nf = 0; nf < 8; ++nf) m = fmaxf(m, acc[mi][nf][r]);
#pragma unroll
            for (int d = 1; d <= 8; d <<= 1) m = fmaxf(m, __shfl_xor(m, d, 64));
            float s = 0.f;
#pragma unroll
            for (int nf = 0; nf < 8; ++nf) s += __expf(acc[mi][nf][r] - m);
#pragma unroll
            for (int d = 1; d <= 8; d <<= 1) s += __shfl_xor(s, d, 64);
            if (lm == 0) {
                redM[wave][mi * 16 + quad * 4 + r] = m;
                redS[wave][mi * 16 + quad * 4 + r] = s;
            }
        }
    __syncthreads();
    if (tid < 32) {
        float m = redM[0][tid];
        m = fmaxf(m, redM[1][tid]); m = fmaxf(m, redM[2][tid]); m = fmaxf(m, redM[3][tid]);
        float s = 0.f;
#pragma unroll
        for (int w = 0; w < 4; ++w) s += redS[w][tid] * __expf(redM[w][tid] - m);
        rowA[tid] = m + __logf(s);   // L1
    }
    __syncthreads();
    float L1[2][4];
#pragma unroll
    for (int mi = 0; mi < 2; ++mi)
#pragma unroll
        for (int r = 0; r < 4; ++r) L1[mi][r] = rowA[mi * 16 + quad * 4 + r];

    const size_t base = ((size_t)b * T1_ + t0) * T2_;
#pragma unroll
    for (int mi = 0; mi < 2; ++mi)
#pragma unroll
        for (int r = 0; r < 4; ++r) {
            size_t rowoff = base + (size_t)(mi * 16 + quad * 4 + r) * T2_;
#pragma unroll
            for (int nf = 0; nf < 8; ++nf) {
                int col = wave * 128 + nf * 16 + lm;
                float pv = prior[rowoff + col];
                float t = acc[mi][nf][r] + __logf(pv + 1e-8f);
                out_logp[rowoff + col] = t - L1[mi][r];
                acc[mi][nf][r] = mk[nf] ? NEG_INF : t;
            }
        }

#pragma unroll
    for (int mi = 0; mi < 2; ++mi)
#pragma unroll
        for (int r = 0; r < 4; ++r) {
            float m = NEG_INF;
#pragma unroll
            for (int nf = 0; nf < 8; ++nf) m = fmaxf(m, acc[mi][nf][r]);
#pragma unroll
            for (int d = 1; d <= 8; d <<= 1) m = fmaxf(m, __shfl_xor(m, d, 64));
            float s = 0.f;
#pragma unroll
            for (int nf = 0; nf < 8; ++nf) s += __expf(acc[mi][nf][r] - m);
#pragma unroll
            for (int d = 1; d <= 8; d <<= 1) s += __shfl_xor(s, d, 64);
            if (lm == 0) {
                redM[wave][mi * 16 + quad * 4 + r] = m;
                redS[wave][mi * 16 + quad * 4 + r] = s;
            }
        }
    __syncthreads();
    if (tid < 32) {
        float m = redM[0][tid];
        m = fmaxf(m, redM[1][tid]); m = fmaxf(m, redM[2][tid]); m = fmaxf(m, redM[3][tid]);
        float s = 0.f;
#pragma unroll
        for (int w = 0; w < 4; ++w) s += redS[w][tid] * __expf(redM[w][tid] - m);
        rowA[tid] = m;
        rowB[tid] = 1.0f / s;
    }
    __syncthreads();

#pragma unroll
    for (int mi = 0; mi < 2; ++mi)
#pragma unroll
        for (int r = 0; r < 4; ++r) {
            int rl = mi * 16 + quad * 4 + r;
            float m2 = rowA[rl], is2 = rowB[rl];
            size_t rowoff = base + (size_t)rl * T2_;
#pragma unroll
            for (int nf = 0; nf < 8; ++nf) {
                int col = wave * 128 + nf * 16 + lm;
                out_attn[rowoff + col] = __expf(acc[mi][nf][r] - m2) * is2;
            }
        }
}

extern "C" void kernel_launch(void* const* d_in, const int* in_sizes, int n_in,
                              void* d_out, int out_size, void* d_ws, size_t ws_size,
                              hipStream_t stream)
{
    const float* queries = (const float*)d_in[0];
    const float* keys    = (const float*)d_in[1];
    const unsigned char* mask = (const unsigned char*)d_in[3];
    const float* prior   = (const float*)d_in[4];
    const float* kW1 = (const float*)d_in[5];
    const float* kb1 = (const float*)d_in[6];
    const float* kW2 = (const float*)d_in[7];
    const float* kb2 = (const float*)d_in[8];
    const float* qW1 = (const float*)d_in[9];
    const float* qb1 = (const float*)d_in[10];
    const float* qW2 = (const float*)d_in[11];
    const float* qb2 = (const float*)d_in[12];
    const float* qW3 = (const float*)d_in[13];
    const float* qb3 = (const float*)d_in[14];

    // workspace (ushort units), ~142.5 MB total:
    unsigned short* ws = (unsigned short*)d_ws;
    unsigned short* keysT    = ws;                       //  32*514*512  = 8,421,376
    unsigned short* queriesT = ws + 8421376;             //  32*2050*128 = 8,396,800
    unsigned short* Bmat2    = ws + 16818176;            //  [32][512][1024]
    unsigned short* Bmat4    = ws + 33595392;            //  [32][2048][256]
    unsigned short* Bmat5    = ws + 50372608;            //  [32][2048][128]
    unsigned short* q_att    = ws + 58761216;            //  [32][2048][128]
    unsigned short* k_att    = ws + 67149824;            //  [32][512][128]
    unsigned short* Wdst     = ws + 69246976;            //  1,851,392 (5 regions)
    unsigned short* Wk1s = Wdst;                         //  [3][1024][512]
    unsigned short* Wk2  = Wdst + 1572864;               //  [128][1024]
    unsigned short* Wq1s = Wdst + 1703936;               //  [3][256][128]
    unsigned short* Wq2  = Wdst + 1802240;               //  [128][256]
    unsigned short* Wq3  = Wdst + 1835008;               //  [128][128]
    float* q2f = (float*)(ws + 71098368);                //  [65536] f32
    float* k2f = q2f + 65536;                            //  [16384] f32

    float* out_attn = (float*)d_out;
    float* out_logp = (float*)d_out + (size_t)B_ * T1_ * T2_;

    dim3 blk(256);
    prep_kernel<<<dim3(17408), blk, 0, stream>>>(queries, keys, kW1, kW2, qW1, qW2, qW3,
                                                 keysT, queriesT, Wdst);

    GArgs a_key1 = {Wk1s, keysT,    kb1, Bmat2, nullptr, 512,  512, 1024,  4, 1, 0, 1024};
    GArgs a_q1   = {Wq1s, queriesT, qb1, Bmat4, nullptr, 128, 2048,  256, 16, 1, 0,  200};
    gemm_pair<3><<<dim3(2048), blk, 0, stream>>>(a_key1, a_q1, 1024);

    GArgs a_key2 = {Wk2, Bmat2, kb2, k_att, k2f,     1024,  512, 128,  4, 0, 1, 100};
    GArgs a_q2   = {Wq2, Bmat4, qb2, Bmat5, nullptr,  256, 2048, 128, 16, 1, 0, 100};
    gemm_pair<1><<<dim3(640), blk, 0, stream>>>(a_key2, a_q2, 128);

    GArgs a_q3   = {Wq3, Bmat5, qb3, q_att, q2f, 128, 2048, 128, 16, 0, 1, 100};
    gemm_pair<1><<<dim3(512), blk, 0, stream>>>(a_q3, a_q3, 512);

    attn_mfma<<<dim3(T1_ / 32, B_), blk, 0, stream>>>(q_att, k_att, q2f, k2f, mask, prior,
                                                      out_attn, out_logp);

    (void)in_sizes; (void)n_in; (void)out_size; (void)ws_size;
}